// Round 3
// baseline (1049.981 us; speedup 1.0000x reference)
//
#include <hip/hip_runtime.h>

#define NEGF (-1e30f)

// ---------------------------------------------------------------------------
// Kernel A: lse[n*512+t] = log( sum_v exp( X[n,t,:]·W[:,v] + b[v] ) )
// 256 blocks (16 per n), 512 threads, 32 rows/block staged in LDS.
// Each thread owns 2 consecutive columns per pass, 4 passes cover V=4096.
// Deterministic reduction: wave shuffle-reduce -> per-wave slot in global
// scratch -> final 8-way sum by wave 0.
// ---------------------------------------------------------------------------
__global__ __launch_bounds__(512, 2) void k_lse(const float* __restrict__ X,
                                                const float* __restrict__ W,
                                                const float* __restrict__ b,
                                                const int* __restrict__ lens,
                                                float* __restrict__ lse,
                                                float* __restrict__ red_g) {
  const int blk = blockIdx.x;          // 0..255
  const int n   = blk >> 4;
  const int t0  = (blk & 15) << 5;     // *32
  if (t0 >= lens[n]) return;           // rows never used downstream
  const int m0 = n * 512 + t0;

  __shared__ float xs[32][512];        // 64 KB exactly
  {
    const float4* Xv = (const float4*)(X + (size_t)m0 * 512);
    float4* xsv = (float4*)(&xs[0][0]);
    for (int i = threadIdx.x; i < 32 * 128; i += 512) xsv[i] = Xv[i];
  }
  float* redb = red_g + (size_t)blk * 256;   // [8 waves][32 rows]
  for (int i = threadIdx.x; i < 256; i += 512) redb[i] = 0.f;
  __syncthreads();

  const int wave = threadIdx.x >> 6;
  const int lane = threadIdx.x & 63;

  for (int j = 0; j < 4; ++j) {
    const int v = (j << 10) + (threadIdx.x << 1);
    const float* Wv = W + v;
    float2 acc[32];
#pragma unroll
    for (int r = 0; r < 32; ++r) acc[r] = make_float2(0.f, 0.f);

    // software-pipelined W loads (4 k-rows ahead)
    float2 w0 = *(const float2*)(Wv + 0 * 4096);
    float2 w1 = *(const float2*)(Wv + 1 * 4096);
    float2 w2 = *(const float2*)(Wv + 2 * 4096);
    float2 w3 = *(const float2*)(Wv + 3 * 4096);
    for (int k4 = 0; k4 < 128; ++k4) {
      const int kn = (k4 + 1) & 127;   // wraps harmlessly on last iter
      float2 p0 = *(const float2*)(Wv + (kn * 4 + 0) * 4096);
      float2 p1 = *(const float2*)(Wv + (kn * 4 + 1) * 4096);
      float2 p2 = *(const float2*)(Wv + (kn * 4 + 2) * 4096);
      float2 p3 = *(const float2*)(Wv + (kn * 4 + 3) * 4096);
#pragma unroll
      for (int r = 0; r < 32; ++r) {
        float4 x4 = *(const float4*)(&xs[r][k4 << 2]);  // broadcast b128
        acc[r].x = fmaf(x4.x, w0.x, acc[r].x);
        acc[r].y = fmaf(x4.x, w0.y, acc[r].y);
        acc[r].x = fmaf(x4.y, w1.x, acc[r].x);
        acc[r].y = fmaf(x4.y, w1.y, acc[r].y);
        acc[r].x = fmaf(x4.z, w2.x, acc[r].x);
        acc[r].y = fmaf(x4.z, w2.y, acc[r].y);
        acc[r].x = fmaf(x4.w, w3.x, acc[r].x);
        acc[r].y = fmaf(x4.w, w3.y, acc[r].y);
      }
      w0 = p0; w1 = p1; w2 = p2; w3 = p3;
    }
    const float2 bb = *(const float2*)(b + v);
#pragma unroll
    for (int r = 0; r < 32; ++r) {
      float e = __expf(acc[r].x + bb.x) + __expf(acc[r].y + bb.y);
#pragma unroll
      for (int off = 32; off > 0; off >>= 1) e += __shfl_xor(e, off);
      if (lane == 0) redb[wave * 32 + r] += e;   // same thread RMW: determ.
    }
  }
  __syncthreads();   // vmcnt(0)-drain + barrier: redb writes visible in block
  if (threadIdx.x < 32) {
    float s = 0.f;
#pragma unroll
    for (int w = 0; w < 8; ++w) s += redb[w * 32 + threadIdx.x];
    lse[m0 + threadIdx.x] = __logf(s);
  }
}

// ---------------------------------------------------------------------------
// Kernel B0: gather the <=129 needed W columns per sample into
// Wgt[n][k][j] (j-contiguous, padded stride 132) + gb[n][j] = b[col].
// col(j) = 0 (blank) for j==0 else labels[n][j-1].
// ---------------------------------------------------------------------------
__global__ void k_gather_w(const float* __restrict__ W,
                           const float* __restrict__ b,
                           const int* __restrict__ labels,
                           float* __restrict__ Wgt,
                           float* __restrict__ gb) {
  const int n  = blockIdx.x >> 7;      // 16 n x 128 k-chunks
  const int kc = blockIdx.x & 127;
  const int k0 = kc << 2;              // 4 k-rows per block
  for (int idx = threadIdx.x; idx < 4 * 129; idx += 256) {
    const int kk = idx / 129;
    const int j  = idx - kk * 129;
    const int c  = (j == 0) ? 0 : labels[n * 128 + (j - 1)];
    const int k  = k0 + kk;
    Wgt[((size_t)(n * 512 + k)) * 132 + j] = W[(size_t)k * 4096 + c];
    if (kc == 0 && kk == 0) gb[n * 129 + j] = b[c];
  }
}

// ---------------------------------------------------------------------------
// Kernel B: g[n*512+t][j] = X[n,t,:]·Wgt[n,:,j] + gb[n,j] - lse[n,t]
// (the gathered log-probs). 256 blocks (32 t-rows each), thread j<129 owns
// one output column across all 32 rows.
// ---------------------------------------------------------------------------
__global__ __launch_bounds__(256) void k_glp(const float* __restrict__ X,
                                             const float* __restrict__ Wgt,
                                             const float* __restrict__ gb,
                                             const float* __restrict__ lse,
                                             const int* __restrict__ lens,
                                             float* __restrict__ g) {
  const int blk = blockIdx.x;
  const int n   = blk >> 4;
  const int t0  = (blk & 15) << 5;
  if (t0 >= lens[n]) return;
  const int m0 = n * 512 + t0;
  __shared__ float xs[32][512];
  {
    const float4* Xv = (const float4*)(X + (size_t)m0 * 512);
    float4* xsv = (float4*)(&xs[0][0]);
    for (int i = threadIdx.x; i < 32 * 128; i += 256) xsv[i] = Xv[i];
  }
  __syncthreads();
  const int j = threadIdx.x;
  if (j >= 129) return;
  const float* wp = Wgt + (size_t)(n * 512) * 132 + j;
  float acc[32];
#pragma unroll
  for (int r = 0; r < 32; ++r) acc[r] = 0.f;

  float w0 = wp[0], w1 = wp[132], w2 = wp[264], w3 = wp[396];
  for (int k4 = 0; k4 < 128; ++k4) {
    const int kn = (k4 + 1) & 127;
    float p0 = wp[(size_t)(kn * 4 + 0) * 132];
    float p1 = wp[(size_t)(kn * 4 + 1) * 132];
    float p2 = wp[(size_t)(kn * 4 + 2) * 132];
    float p3 = wp[(size_t)(kn * 4 + 3) * 132];
#pragma unroll
    for (int r = 0; r < 32; ++r) {
      float4 x4 = *(const float4*)(&xs[r][k4 << 2]);
      acc[r] = fmaf(x4.x, w0, acc[r]);
      acc[r] = fmaf(x4.y, w1, acc[r]);
      acc[r] = fmaf(x4.z, w2, acc[r]);
      acc[r] = fmaf(x4.w, w3, acc[r]);
    }
    w0 = p0; w1 = p1; w2 = p2; w3 = p3;
  }
  const float bb = gb[n * 129 + j];
#pragma unroll
  for (int r = 0; r < 32; ++r)
    g[(size_t)(m0 + r) * 132 + j] = acc[r] + bb - lse[m0 + r];
}

// ---------------------------------------------------------------------------
// Kernel C: CTC alpha recursion. One 64-lane wave per sample; 5 states per
// lane held in registers (s = 5*lane + i). Cross-lane neighbors via
// __shfl_up only. Loop runs to input_lens[n]-1 (alpha frozen afterwards).
// ---------------------------------------------------------------------------
__device__ __forceinline__ float lae3(float x, float y, float z) {
  float m = fmaxf(fmaxf(x, y), z);
  float e = exp2f((x - m) * 1.44269504f)
          + exp2f((y - m) * 1.44269504f)
          + exp2f((z - m) * 1.44269504f);
  return m + 0.69314718f * log2f(e);
}

__global__ void k_ctc(const float* __restrict__ g,
                      const int* __restrict__ labels,
                      const int* __restrict__ in_lens,
                      const int* __restrict__ lab_lens,
                      float* __restrict__ nll) {
  const int n = blockIdx.x;
  const int l = threadIdx.x;           // 64 threads = 1 wave
  const float* gn = g + (size_t)n * 512 * 132;
  const int len = in_lens[n];
  const int s0 = 5 * l;

  int jm[5]; bool sk[5];
#pragma unroll
  for (int i = 0; i < 5; ++i) {
    const int s = s0 + i;
    const bool valid = (s < 257);
    jm[i] = (valid && (s & 1)) ? ((s + 1) >> 1) : 0;
    sk[i] = false;
    if (valid && (s & 1) && s >= 3) {
      const int li = (s - 1) >> 1;
      const int cl = labels[n * 128 + li];
      sk[i] = (cl != 0) && (cl != labels[n * 128 + li - 1]);
    }
  }

  float a[5];
  a[0] = (l == 0) ? gn[0] : NEGF;      // s=0: blank at t=0
  a[1] = (l == 0) ? gn[1] : NEGF;      // s=1: first label at t=0
  a[2] = NEGF; a[3] = NEGF; a[4] = NEGF;

  float lp[5];
#pragma unroll
  for (int i = 0; i < 5; ++i) lp[i] = gn[132 + jm[i]];  // t=1

  for (int t = 1; t < len; ++t) {
    const int tp = (t + 1 < len) ? (t + 1) : t;   // prefetch next (clamped)
    float np[5];
#pragma unroll
    for (int i = 0; i < 5; ++i) np[i] = gn[(size_t)tp * 132 + jm[i]];

    float a3p = __shfl_up(a[3], 1);
    float a4p = __shfl_up(a[4], 1);
    if (l == 0) { a3p = NEGF; a4p = NEGF; }

    const float b0 = lae3(a[0], a4p,  sk[0] ? a3p  : NEGF) + lp[0];
    const float b1 = lae3(a[1], a[0], sk[1] ? a4p  : NEGF) + lp[1];
    const float b2 = lae3(a[2], a[1], sk[2] ? a[0] : NEGF) + lp[2];
    const float b3 = lae3(a[3], a[2], sk[3] ? a[1] : NEGF) + lp[3];
    const float b4 = lae3(a[4], a[3], sk[4] ? a[2] : NEGF) + lp[4];
    a[0] = b0; a[1] = b1; a[2] = b2; a[3] = b3; a[4] = b4;
#pragma unroll
    for (int i = 0; i < 5; ++i) lp[i] = np[i];
  }

  __shared__ float al[320];
#pragma unroll
  for (int i = 0; i < 5; ++i) al[s0 + i] = a[i];
  __syncthreads();
  if (l == 0) {
    const int ll  = lab_lens[n];
    const int idx = 2 * ll;
    const float e1 = al[idx], e2 = al[idx - 1];
    const float m = fmaxf(e1, e2);
    const float r = m + 0.69314718f * log2f(exp2f((e1 - m) * 1.44269504f) +
                                            exp2f((e2 - m) * 1.44269504f));
    nll[n] = -r;
  }
}

// ---------------------------------------------------------------------------
// Kernel D: out = sum(nll)/16
// ---------------------------------------------------------------------------
__global__ void k_finish(const float* __restrict__ nll, float* __restrict__ out) {
  const int l = threadIdx.x;
  float v = (l < 16) ? nll[l] : 0.f;
#pragma unroll
  for (int off = 8; off > 0; off >>= 1) v += __shfl_down(v, off);
  if (l == 0) out[0] = v * 0.0625f;
}

// ---------------------------------------------------------------------------
extern "C" void kernel_launch(void* const* d_in, const int* in_sizes, int n_in,
                              void* d_out, int out_size, void* d_ws, size_t ws_size,
                              hipStream_t stream) {
  const float* X        = (const float*)d_in[0];   // (16,512,512)
  const float* W        = (const float*)d_in[1];   // (512,4096)
  const float* b        = (const float*)d_in[2];   // (4096)
  const int*   in_lens  = (const int*)d_in[3];     // (16)
  const int*   labels   = (const int*)d_in[4];     // (16,128)
  const int*   lab_lens = (const int*)d_in[5];     // (16)
  float* out = (float*)d_out;

  // workspace layout (floats)
  float* ws    = (float*)d_ws;
  float* lse   = ws;                                   // 8192
  float* red_g = ws + 8192;                            // 65536 (256 blk * 256)
  float* Wgt   = ws + 8192 + 65536;                    // 1081344 (16*512*132)
  float* gb    = Wgt + 1081344;                        // 2064 (16*129)
  float* g     = gb + 2064;                            // 1081344
  float* nll   = g + 1081344;                          // 16

  k_lse<<<dim3(256), dim3(512), 0, stream>>>(X, W, b, in_lens, lse, red_g);
  k_gather_w<<<dim3(2048), dim3(256), 0, stream>>>(W, b, labels, Wgt, gb);
  k_glp<<<dim3(256), dim3(256), 0, stream>>>(X, Wgt, gb, lse, in_lens, g);
  k_ctc<<<dim3(16), dim3(64), 0, stream>>>(g, labels, in_lens, lab_lens, nll);
  k_finish<<<dim3(1), dim3(64), 0, stream>>>(nll, out);
}

// Round 4
// 400.102 us; speedup vs baseline: 2.6243x; 2.6243x over previous
//
#include <hip/hip_runtime.h>

#define NEGF (-1e30f)

typedef __attribute__((ext_vector_type(8))) short bf16x8;
typedef __attribute__((ext_vector_type(4))) float f32x4;

__device__ __forceinline__ unsigned short f2bf(float x) {
  unsigned u = __float_as_uint(x);
  unsigned r = (u + 0x7FFFu + ((u >> 16) & 1u)) >> 16;
  return (unsigned short)r;
}
__device__ __forceinline__ float bf2f(unsigned short h) {
  return __uint_as_float(((unsigned)h) << 16);
}

// ---------------------------------------------------------------------------
// k_splitx: X (fp32, 8192x512) -> Xhi, Xlo (bf16 as ushort).
// ---------------------------------------------------------------------------
__global__ __launch_bounds__(256) void k_splitx(const float* __restrict__ X,
                                                unsigned short* __restrict__ Xhi,
                                                unsigned short* __restrict__ Xlo) {
  const int i = blockIdx.x * 256 + threadIdx.x;   // float4 index, 1048576 total
  float4 v = ((const float4*)X)[i];
  ushort4 h, l;
  h.x = f2bf(v.x); l.x = f2bf(v.x - bf2f(h.x));
  h.y = f2bf(v.y); l.y = f2bf(v.y - bf2f(h.y));
  h.z = f2bf(v.z); l.z = f2bf(v.z - bf2f(h.z));
  h.w = f2bf(v.w); l.w = f2bf(v.w - bf2f(h.w));
  ((ushort4*)Xhi)[i] = h;
  ((ushort4*)Xlo)[i] = l;
}

// ---------------------------------------------------------------------------
// k_wtrans: W (fp32, 512x4096 row-major) -> Wt hi/lo (bf16, 4096x512).
// 64x64 tiles via LDS.
// ---------------------------------------------------------------------------
__global__ __launch_bounds__(256) void k_wtrans(const float* __restrict__ W,
                                                unsigned short* __restrict__ Wth,
                                                unsigned short* __restrict__ Wtl) {
  __shared__ float tile[64][65];
  const int kb = blockIdx.x & 7;    // 512/64
  const int vb = blockIdx.x >> 3;   // 4096/64
  const int k0 = kb << 6, v0 = vb << 6;
#pragma unroll
  for (int it = 0; it < 16; ++it) {
    const int idx = it * 256 + threadIdx.x;
    const int r = idx >> 6, c = idx & 63;
    tile[r][c] = W[(size_t)(k0 + r) * 4096 + v0 + c];
  }
  __syncthreads();
#pragma unroll
  for (int it = 0; it < 16; ++it) {
    const int idx = it * 256 + threadIdx.x;
    const int vr = idx >> 6, kc = idx & 63;
    const float val = tile[kc][vr];
    const unsigned short h = f2bf(val);
    Wth[(size_t)(v0 + vr) * 512 + k0 + kc] = h;
    Wtl[(size_t)(v0 + vr) * 512 + k0 + kc] = f2bf(val - bf2f(h));
  }
}

// ---------------------------------------------------------------------------
// k_gemm: split-bf16 MFMA GEMM, fused exp-row-sum epilogue.
// Tile 128x128, BK=32, 256 threads (4 waves, 2x2), double-buffered LDS,
// global_load_lds width-16 staging (T3 2-phase schedule).
// Writes pg[m][bn] = sum_{v in block} exp(logit[m][v] + bias[v]).
// ---------------------------------------------------------------------------
__device__ __forceinline__ void stage_tile(const unsigned short* __restrict__ src,
                                           int r0, char* ldsbase, int wave,
                                           int tid, int kbyte) {
#pragma unroll
  for (int j = 0; j < 2; ++j) {
    const char* gp = (const char*)src +
        (size_t)(r0 + j * 64 + (tid >> 2)) * 1024 + kbyte + (tid & 3) * 16;
    char* lp = ldsbase + j * 4096 + wave * 1024;
    __builtin_amdgcn_global_load_lds(
        (const __attribute__((address_space(1))) unsigned int*)gp,
        (__attribute__((address_space(3))) unsigned int*)lp, 16, 0, 0);
  }
}

__global__ __launch_bounds__(256, 2) void k_gemm(const unsigned short* __restrict__ Xhi,
                                                 const unsigned short* __restrict__ Xlo,
                                                 const unsigned short* __restrict__ Wth,
                                                 const unsigned short* __restrict__ Wtl,
                                                 const float* __restrict__ bvec,
                                                 const int* __restrict__ lens,
                                                 float* __restrict__ pg) {
  const int bm = blockIdx.x >> 5;   // 0..63  (m-tile)
  const int bn = blockIdx.x & 31;   // 0..31  (v-tile)
  const int n  = bm >> 2;
  const int t0 = (bm & 3) << 7;
  if (t0 >= lens[n]) return;        // block-uniform exit
  const int m0 = bm << 7;
  const int v0 = bn << 7;

  __shared__ __align__(16) char smem[66560];  // 2 x 32KB dbuf + 1KB part
  const int tid  = threadIdx.x;
  const int wave = tid >> 6;
  const int lane = tid & 63;
  const int lrow = lane & 15;
  const int lk   = (lane >> 4) * 16;
  const int wr   = wave >> 1;       // wave row (0..1) -> rows wr*64..+63
  const int wn   = wave & 1;        // wave col       -> cols wn*64..+63

  f32x4 acc[4][4];
#pragma unroll
  for (int mi = 0; mi < 4; ++mi)
#pragma unroll
    for (int ni = 0; ni < 4; ++ni) acc[mi][ni] = (f32x4){0.f, 0.f, 0.f, 0.f};

  // prologue: stage K-step 0 into buffer 0
  {
    char* buf = smem;
    stage_tile(Xhi, m0, buf + 0,     wave, tid, 0);
    stage_tile(Xlo, m0, buf + 8192,  wave, tid, 0);
    stage_tile(Wth, v0, buf + 16384, wave, tid, 0);
    stage_tile(Wtl, v0, buf + 24576, wave, tid, 0);
  }
  __syncthreads();

  int cur = 0;
  for (int kk = 0; kk < 16; ++kk) {
    if (kk < 15) {                  // issue next-tile loads first (T3)
      char* nbuf = smem + (cur ^ 1) * 32768;
      const int kb = (kk + 1) << 6;
      stage_tile(Xhi, m0, nbuf + 0,     wave, tid, kb);
      stage_tile(Xlo, m0, nbuf + 8192,  wave, tid, kb);
      stage_tile(Wth, v0, nbuf + 16384, wave, tid, kb);
      stage_tile(Wtl, v0, nbuf + 24576, wave, tid, kb);
    }
    const char* buf = smem + cur * 32768;
    bf16x8 ah[4], al[4], bh[4], bl[4];
#pragma unroll
    for (int mi = 0; mi < 4; ++mi) {
      const int off = (wr * 64 + mi * 16 + lrow) * 64 + lk;
      ah[mi] = *(const bf16x8*)(buf + off);
      al[mi] = *(const bf16x8*)(buf + 8192 + off);
    }
#pragma unroll
    for (int ni = 0; ni < 4; ++ni) {
      const int off = (wn * 64 + ni * 16 + lrow) * 64 + lk;
      bh[ni] = *(const bf16x8*)(buf + 16384 + off);
      bl[ni] = *(const bf16x8*)(buf + 24576 + off);
    }
#pragma unroll
    for (int mi = 0; mi < 4; ++mi)
#pragma unroll
      for (int ni = 0; ni < 4; ++ni) {
        acc[mi][ni] = __builtin_amdgcn_mfma_f32_16x16x32_bf16(ah[mi], bh[ni], acc[mi][ni], 0, 0, 0);
        acc[mi][ni] = __builtin_amdgcn_mfma_f32_16x16x32_bf16(ah[mi], bl[ni], acc[mi][ni], 0, 0, 0);
        acc[mi][ni] = __builtin_amdgcn_mfma_f32_16x16x32_bf16(al[mi], bh[ni], acc[mi][ni], 0, 0, 0);
      }
    __syncthreads();
    cur ^= 1;
  }

  // epilogue: exp + row-sum over this block's 128 columns (deterministic)
  const float lg2e = 1.4426950408889634f;
  float bias[4];
#pragma unroll
  for (int ni = 0; ni < 4; ++ni) bias[ni] = bvec[v0 + wn * 64 + ni * 16 + lrow];
  float* part = (float*)(smem + 65536);   // [128][2]
#pragma unroll
  for (int mi = 0; mi < 4; ++mi)
#pragma unroll
    for (int reg = 0; reg < 4; ++reg) {
      float s = 0.f;
#pragma unroll
      for (int ni = 0; ni < 4; ++ni)
        s += exp2f((acc[mi][ni][reg] + bias[ni]) * lg2e);
#pragma unroll
      for (int msk = 1; msk < 16; msk <<= 1) s += __shfl_xor(s, msk);
      if (lrow == 0)
        part[(wr * 64 + mi * 16 + (lane >> 4) * 4 + reg) * 2 + wn] = s;
    }
  __syncthreads();
  if (tid < 128)
    pg[(size_t)(m0 + tid) * 32 + bn] = part[tid * 2 + 0] + part[tid * 2 + 1];
}

// ---------------------------------------------------------------------------
// k_lsefin: lse[m] = log( sum_{bn} pg[m][bn] )   (rows with t>=len -> 0)
// ---------------------------------------------------------------------------
__global__ __launch_bounds__(256) void k_lsefin(const float* __restrict__ pg,
                                                const int* __restrict__ lens,
                                                float* __restrict__ lse) {
  const int m = blockIdx.x * 256 + threadIdx.x;   // 8192
  const int n = m >> 9, t = m & 511;
  if (t >= lens[n]) { lse[m] = 0.f; return; }
  const float4* p = (const float4*)(pg + (size_t)m * 32);
  float s = 0.f;
#pragma unroll
  for (int i = 0; i < 8; ++i) { float4 v = p[i]; s += v.x + v.y + v.z + v.w; }
  lse[m] = __logf(s);
}

// ---------------------------------------------------------------------------
// FALLBACK kernel (round-3 k_lse) — used only if ws_size is too small.
// ---------------------------------------------------------------------------
__global__ __launch_bounds__(512, 2) void k_lse(const float* __restrict__ X,
                                                const float* __restrict__ W,
                                                const float* __restrict__ b,
                                                const int* __restrict__ lens,
                                                float* __restrict__ lse,
                                                float* __restrict__ red_g) {
  const int blk = blockIdx.x;
  const int n   = blk >> 4;
  const int t0  = (blk & 15) << 5;
  if (t0 >= lens[n]) return;
  const int m0 = n * 512 + t0;
  __shared__ float xs[32][512];
  {
    const float4* Xv = (const float4*)(X + (size_t)m0 * 512);
    float4* xsv = (float4*)(&xs[0][0]);
    for (int i = threadIdx.x; i < 32 * 128; i += 512) xsv[i] = Xv[i];
  }
  float* redb = red_g + (size_t)blk * 256;
  for (int i = threadIdx.x; i < 256; i += 512) redb[i] = 0.f;
  __syncthreads();
  const int wave = threadIdx.x >> 6;
  const int lane = threadIdx.x & 63;
  for (int j = 0; j < 4; ++j) {
    const int v = (j << 10) + (threadIdx.x << 1);
    const float* Wv = W + v;
    float2 acc[32];
#pragma unroll
    for (int r = 0; r < 32; ++r) acc[r] = make_float2(0.f, 0.f);
    float2 w0 = *(const float2*)(Wv + 0 * 4096);
    float2 w1 = *(const float2*)(Wv + 1 * 4096);
    float2 w2 = *(const float2*)(Wv + 2 * 4096);
    float2 w3 = *(const float2*)(Wv + 3 * 4096);
    for (int k4 = 0; k4 < 128; ++k4) {
      const int kn = (k4 + 1) & 127;
      float2 p0 = *(const float2*)(Wv + (kn * 4 + 0) * 4096);
      float2 p1 = *(const float2*)(Wv + (kn * 4 + 1) * 4096);
      float2 p2 = *(const float2*)(Wv + (kn * 4 + 2) * 4096);
      float2 p3 = *(const float2*)(Wv + (kn * 4 + 3) * 4096);
#pragma unroll
      for (int r = 0; r < 32; ++r) {
        float4 x4 = *(const float4*)(&xs[r][k4 << 2]);
        acc[r].x = fmaf(x4.x, w0.x, acc[r].x);
        acc[r].y = fmaf(x4.x, w0.y, acc[r].y);
        acc[r].x = fmaf(x4.y, w1.x, acc[r].x);
        acc[r].y = fmaf(x4.y, w1.y, acc[r].y);
        acc[r].x = fmaf(x4.z, w2.x, acc[r].x);
        acc[r].y = fmaf(x4.z, w2.y, acc[r].y);
        acc[r].x = fmaf(x4.w, w3.x, acc[r].x);
        acc[r].y = fmaf(x4.w, w3.y, acc[r].y);
      }
      w0 = p0; w1 = p1; w2 = p2; w3 = p3;
    }
    const float2 bb = *(const float2*)(b + v);
#pragma unroll
    for (int r = 0; r < 32; ++r) {
      float e = __expf(acc[r].x + bb.x) + __expf(acc[r].y + bb.y);
#pragma unroll
      for (int off = 32; off > 0; off >>= 1) e += __shfl_xor(e, off);
      if (lane == 0) redb[wave * 32 + r] += e;
    }
  }
  __syncthreads();
  if (threadIdx.x < 32) {
    float s = 0.f;
#pragma unroll
    for (int w = 0; w < 8; ++w) s += redb[w * 32 + threadIdx.x];
    lse[m0 + threadIdx.x] = __logf(s);
  }
}

// ---------------------------------------------------------------------------
// k_gather_w / k_glp / k_ctc / k_finish — unchanged (validated, absmax 0.0).
// ---------------------------------------------------------------------------
__global__ void k_gather_w(const float* __restrict__ W,
                           const float* __restrict__ b,
                           const int* __restrict__ labels,
                           float* __restrict__ Wgt,
                           float* __restrict__ gb) {
  const int n  = blockIdx.x >> 7;
  const int kc = blockIdx.x & 127;
  const int k0 = kc << 2;
  for (int idx = threadIdx.x; idx < 4 * 129; idx += 256) {
    const int kk = idx / 129;
    const int j  = idx - kk * 129;
    const int c  = (j == 0) ? 0 : labels[n * 128 + (j - 1)];
    const int k  = k0 + kk;
    Wgt[((size_t)(n * 512 + k)) * 132 + j] = W[(size_t)k * 4096 + c];
    if (kc == 0 && kk == 0) gb[n * 129 + j] = b[c];
  }
}

__global__ __launch_bounds__(256) void k_glp(const float* __restrict__ X,
                                             const float* __restrict__ Wgt,
                                             const float* __restrict__ gb,
                                             const float* __restrict__ lse,
                                             const int* __restrict__ lens,
                                             float* __restrict__ g) {
  const int blk = blockIdx.x;
  const int n   = blk >> 4;
  const int t0  = (blk & 15) << 5;
  if (t0 >= lens[n]) return;
  const int m0 = n * 512 + t0;
  __shared__ float xs[32][512];
  {
    const float4* Xv = (const float4*)(X + (size_t)m0 * 512);
    float4* xsv = (float4*)(&xs[0][0]);
    for (int i = threadIdx.x; i < 32 * 128; i += 256) xsv[i] = Xv[i];
  }
  __syncthreads();
  const int j = threadIdx.x;
  if (j >= 129) return;
  const float* wp = Wgt + (size_t)(n * 512) * 132 + j;
  float acc[32];
#pragma unroll
  for (int r = 0; r < 32; ++r) acc[r] = 0.f;
  float w0 = wp[0], w1 = wp[132], w2 = wp[264], w3 = wp[396];
  for (int k4 = 0; k4 < 128; ++k4) {
    const int kn = (k4 + 1) & 127;
    float p0 = wp[(size_t)(kn * 4 + 0) * 132];
    float p1 = wp[(size_t)(kn * 4 + 1) * 132];
    float p2 = wp[(size_t)(kn * 4 + 2) * 132];
    float p3 = wp[(size_t)(kn * 4 + 3) * 132];
#pragma unroll
    for (int r = 0; r < 32; ++r) {
      float4 x4 = *(const float4*)(&xs[r][k4 << 2]);
      acc[r] = fmaf(x4.x, w0, acc[r]);
      acc[r] = fmaf(x4.y, w1, acc[r]);
      acc[r] = fmaf(x4.z, w2, acc[r]);
      acc[r] = fmaf(x4.w, w3, acc[r]);
    }
    w0 = p0; w1 = p1; w2 = p2; w3 = p3;
  }
  const float bb = gb[n * 129 + j];
#pragma unroll
  for (int r = 0; r < 32; ++r)
    g[(size_t)(m0 + r) * 132 + j] = acc[r] + bb - lse[m0 + r];
}

__device__ __forceinline__ float lae3(float x, float y, float z) {
  float m = fmaxf(fmaxf(x, y), z);
  float e = exp2f((x - m) * 1.44269504f)
          + exp2f((y - m) * 1.44269504f)
          + exp2f((z - m) * 1.44269504f);
  return m + 0.69314718f * log2f(e);
}

__global__ void k_ctc(const float* __restrict__ g,
                      const int* __restrict__ labels,
                      const int* __restrict__ in_lens,
                      const int* __restrict__ lab_lens,
                      float* __restrict__ nll) {
  const int n = blockIdx.x;
  const int l = threadIdx.x;
  const float* gn = g + (size_t)n * 512 * 132;
  const int len = in_lens[n];
  const int s0 = 5 * l;
  int jm[5]; bool sk[5];
#pragma unroll
  for (int i = 0; i < 5; ++i) {
    const int s = s0 + i;
    const bool valid = (s < 257);
    jm[i] = (valid && (s & 1)) ? ((s + 1) >> 1) : 0;
    sk[i] = false;
    if (valid && (s & 1) && s >= 3) {
      const int li = (s - 1) >> 1;
      const int cl = labels[n * 128 + li];
      sk[i] = (cl != 0) && (cl != labels[n * 128 + li - 1]);
    }
  }
  float a[5];
  a[0] = (l == 0) ? gn[0] : NEGF;
  a[1] = (l == 0) ? gn[1] : NEGF;
  a[2] = NEGF; a[3] = NEGF; a[4] = NEGF;
  float lp[5];
#pragma unroll
  for (int i = 0; i < 5; ++i) lp[i] = gn[132 + jm[i]];
  for (int t = 1; t < len; ++t) {
    const int tp = (t + 1 < len) ? (t + 1) : t;
    float np[5];
#pragma unroll
    for (int i = 0; i < 5; ++i) np[i] = gn[(size_t)tp * 132 + jm[i]];
    float a3p = __shfl_up(a[3], 1);
    float a4p = __shfl_up(a[4], 1);
    if (l == 0) { a3p = NEGF; a4p = NEGF; }
    const float b0 = lae3(a[0], a4p,  sk[0] ? a3p  : NEGF) + lp[0];
    const float b1 = lae3(a[1], a[0], sk[1] ? a4p  : NEGF) + lp[1];
    const float b2 = lae3(a[2], a[1], sk[2] ? a[0] : NEGF) + lp[2];
    const float b3 = lae3(a[3], a[2], sk[3] ? a[1] : NEGF) + lp[3];
    const float b4 = lae3(a[4], a[3], sk[4] ? a[2] : NEGF) + lp[4];
    a[0] = b0; a[1] = b1; a[2] = b2; a[3] = b3; a[4] = b4;
#pragma unroll
    for (int i = 0; i < 5; ++i) lp[i] = np[i];
  }
  __shared__ float al[320];
#pragma unroll
  for (int i = 0; i < 5; ++i) al[s0 + i] = a[i];
  __syncthreads();
  if (l == 0) {
    const int ll  = lab_lens[n];
    const int idx = 2 * ll;
    const float e1 = al[idx], e2 = al[idx - 1];
    const float m = fmaxf(e1, e2);
    const float r = m + 0.69314718f * log2f(exp2f((e1 - m) * 1.44269504f) +
                                            exp2f((e2 - m) * 1.44269504f));
    nll[n] = -r;
  }
}

__global__ void k_finish(const float* __restrict__ nll, float* __restrict__ out) {
  const int l = threadIdx.x;
  float v = (l < 16) ? nll[l] : 0.f;
#pragma unroll
  for (int off = 8; off > 0; off >>= 1) v += __shfl_down(v, off);
  if (l == 0) out[0] = v * 0.0625f;
}

// ---------------------------------------------------------------------------
extern "C" void kernel_launch(void* const* d_in, const int* in_sizes, int n_in,
                              void* d_out, int out_size, void* d_ws, size_t ws_size,
                              hipStream_t stream) {
  const float* X        = (const float*)d_in[0];   // (16,512,512)
  const float* W        = (const float*)d_in[1];   // (512,4096)
  const float* b        = (const float*)d_in[2];   // (4096)
  const int*   in_lens  = (const int*)d_in[3];     // (16)
  const int*   labels   = (const int*)d_in[4];     // (16,128)
  const int*   lab_lens = (const int*)d_in[5];     // (16)
  float* out = (float*)d_out;
  char* wsb = (char*)d_ws;

  const size_t NEED = 34906112;   // bytes for the MFMA path
  if (ws_size >= NEED) {
    // byte offsets (all 16B-aligned)
    float* lse = (float*)(wsb + 0);          //  8192 f
    float* pg  = (float*)(wsb + 32768);      //  8192*32 f
    float* Wgt = (float*)(wsb + 1081344);    //  16*512*132 f
    float* gb  = (float*)(wsb + 5406720);    //  16*129 f
    float* g   = (float*)(wsb + 5414976);    //  16*512*132 f
    float* nll = (float*)(wsb + 9740352);    //  16 f
    unsigned short* Xhi = (unsigned short*)(wsb + 9740416);
    unsigned short* Xlo = (unsigned short*)(wsb + 18128896);
    unsigned short* Wth = (unsigned short*)(wsb + 26517504);
    unsigned short* Wtl = (unsigned short*)(wsb + 30711808);

    k_splitx<<<dim3(4096), dim3(256), 0, stream>>>(X, Xhi, Xlo);
    k_wtrans<<<dim3(512), dim3(256), 0, stream>>>(W, Wth, Wtl);
    k_gemm<<<dim3(2048), dim3(256), 0, stream>>>(Xhi, Xlo, Wth, Wtl, b, in_lens, pg);
    k_lsefin<<<dim3(32), dim3(256), 0, stream>>>(pg, in_lens, lse);
    k_gather_w<<<dim3(2048), dim3(256), 0, stream>>>(W, b, labels, Wgt, gb);
    k_glp<<<dim3(256), dim3(256), 0, stream>>>(X, Wgt, gb, lse, in_lens, g);
    k_ctc<<<dim3(16), dim3(64), 0, stream>>>(g, labels, in_lens, lab_lens, nll);
    k_finish<<<dim3(1), dim3(64), 0, stream>>>(nll, out);
  } else {
    // round-3 fallback layout (floats)
    float* ws    = (float*)d_ws;
    float* lse   = ws;
    float* red_g = ws + 8192;
    float* Wgt   = ws + 8192 + 65536;
    float* gb    = Wgt + 1081344;
    float* g     = gb + 2064;
    float* nll   = g + 1081344;
    k_lse<<<dim3(256), dim3(512), 0, stream>>>(X, W, b, in_lens, lse, red_g);
    k_gather_w<<<dim3(2048), dim3(256), 0, stream>>>(W, b, labels, Wgt, gb);
    k_glp<<<dim3(256), dim3(256), 0, stream>>>(X, Wgt, gb, lse, in_lens, g);
    k_ctc<<<dim3(16), dim3(64), 0, stream>>>(g, labels, in_lens, lab_lens, nll);
    k_finish<<<dim3(1), dim3(64), 0, stream>>>(nll, out);
  }
}